// Round 1
// baseline (31.458 us; speedup 1.0000x reference)
//
#include <hip/hip_runtime.h>

#define NC   80     // classes
#define CCH  85     // channels = 5 + NC
#define NBATCH 32

// scale geometry
#define HW0 6400    // 80*80
#define HW1 1600    // 40*40
#define HW2 400     // 20*20
#define NCELL0 (NBATCH*HW0)   // 204800
#define NCELL1 (NBATCH*HW1)   // 51200
#define NCELL2 (NBATCH*HW2)   // 12800
#define NCELL_TOT (NCELL0+NCELL1+NCELL2)  // 268800

#define OBJ_BLOCKS 240

static __device__ __forceinline__ float softplus_ref(float x) {
    return fmaxf(x, 0.f) + log1pf(expf(-fabsf(x)));
}

// ---------------- K0: zero marks + accumulators ----------------
__global__ void k_zero(unsigned int* __restrict__ marks_u32, int nwords,
                       float* __restrict__ acc_obj, unsigned int* __restrict__ counter) {
    int i = blockIdx.x * blockDim.x + threadIdx.x;
    int stride = gridDim.x * blockDim.x;
    for (; i < nwords; i += stride) marks_u32[i] = 0u;
    if (blockIdx.x == 0 && threadIdx.x == 0) {
        *acc_obj = 0.f;
        *counter = 0u;
    }
}

// ---------------- K1: per-target gather (16 lanes per target) ----------------
__global__ void k_targets(const float* __restrict__ p0, const float* __restrict__ p1,
                          const float* __restrict__ p2, const float* __restrict__ tgt,
                          int n,
                          float* __restrict__ box_part, float* __restrict__ cls_part,
                          unsigned char* __restrict__ marks) {
    int gid  = blockIdx.x * blockDim.x + threadIdx.x;
    int t    = gid >> 4;
    int lane = gid & 15;

    float cls_sum = 0.f;
    float box_sum = 0.f;

    if (t < n) {
        const float* tr = tgt + (size_t)t * 6;
        int   b   = (int)tr[0];
        int   cls = (int)tr[1];
        float cx = tr[2], cy = tr[3], bw = tr[4], bh = tr[5];

        float area = fmaxf(bw * bh, 1e-6f);
        int s = (area <= 0.01f) ? 0 : ((area <= 0.03f) ? 1 : 2);
        int w = 80 >> s, h = 80 >> s, hw = w * h;
        const float* pred = (s == 0) ? p0 : ((s == 1) ? p1 : p2);

        int gx = (int)(cx * (float)w); gx = min(max(gx, 0), w - 1);
        int gy = (int)(cy * (float)h); gy = min(max(gy, 0), h - 1);

        const float* base = pred + (size_t)b * CCH * hw + (size_t)gy * w + gx;

        // class BCE: lane handles classes [lane*5, lane*5+5)
        #pragma unroll
        for (int k = 0; k < 5; k++) {
            int c = lane * 5 + k;
            float x  = base[(size_t)(5 + c) * hw];
            float tv = (c == cls) ? 1.f : 0.f;
            cls_sum += fmaxf(x, 0.f) - x * tv + log1pf(expf(-fabsf(x)));
        }
        cls_sum *= (1.f / (float)NC);

        if (lane == 0) {
            float pv0 = base[0];
            float pv1 = base[(size_t)hw];
            float pv2 = base[(size_t)2 * hw];
            float pv3 = base[(size_t)3 * hw];
            float px = (1.f / (1.f + expf(-pv0)) + (float)gx) / (float)w;
            float py = (1.f / (1.f + expf(-pv1)) + (float)gy) / (float)h;
            float pw = expf(fminf(pv2, 4.f)) / (float)w;
            float ph = expf(fminf(pv3, 4.f)) / (float)h;
            float l1 = (fabsf(px - cx) + fabsf(py - cy) + fabsf(pw - bw) + fabsf(ph - bh)) * 0.25f;
            float weight = 1.f + 2.f * (1.f - sqrtf(area));
            box_sum = l1 * weight;

            int cellbase = (s == 0) ? 0 : ((s == 1) ? NCELL0 : (NCELL0 + NCELL1));
            int cell = cellbase + b * hw + gy * w + gx;
            marks[cell] = 1;   // same-value byte writes: race-free, reproduces scatter-max
        }
    }

    __shared__ float red[256];
    int tid = threadIdx.x;
    red[tid] = cls_sum; __syncthreads();
    for (int off = 128; off > 0; off >>= 1) { if (tid < off) red[tid] += red[tid + off]; __syncthreads(); }
    if (tid == 0) cls_part[blockIdx.x] = red[0];
    __syncthreads();
    red[tid] = box_sum; __syncthreads();
    for (int off = 128; off > 0; off >>= 1) { if (tid < off) red[tid] += red[tid + off]; __syncthreads(); }
    if (tid == 0) box_part[blockIdx.x] = red[0];
}

// ---------------- K2: objectness BCE sweep + finalize ----------------
template <int HW, int NCELLS, int CELLBASE>
static __device__ __forceinline__ void obj_scale_loop(
        const float* __restrict__ pred, const unsigned char* __restrict__ marks,
        float inv_norm, float& acc, int gtid, int gstride) {
    const int NG = NCELLS / 4;
    for (int g = gtid; g < NG; g += gstride) {
        int cell = g * 4;
        int b    = cell / HW;
        int pos  = cell - b * HW;
        const float4 x4 = *reinterpret_cast<const float4*>(
            pred + (size_t)b * CCH * HW + (size_t)4 * HW + pos);
        uchar4 m4 = *reinterpret_cast<const uchar4*>(marks + CELLBASE + cell);
        float ssum = softplus_ref(x4.x) - x4.x * (float)m4.x
                   + softplus_ref(x4.y) - x4.y * (float)m4.y
                   + softplus_ref(x4.z) - x4.z * (float)m4.z
                   + softplus_ref(x4.w) - x4.w * (float)m4.w;
        acc += ssum * inv_norm;
    }
}

__global__ void k_obj(const float* __restrict__ p0, const float* __restrict__ p1,
                      const float* __restrict__ p2, const unsigned char* __restrict__ marks,
                      const float* box_part, const float* cls_part,
                      int nblocks_t, float inv_n,
                      float* acc_obj, unsigned int* counter,
                      float* __restrict__ out) {
    int gtid    = blockIdx.x * blockDim.x + threadIdx.x;
    int gstride = gridDim.x * blockDim.x;
    float acc = 0.f;
    obj_scale_loop<HW0, NCELL0, 0>              (p0, marks, 1.f / (float)NCELL0, acc, gtid, gstride);
    obj_scale_loop<HW1, NCELL1, NCELL0>         (p1, marks, 1.f / (float)NCELL1, acc, gtid, gstride);
    obj_scale_loop<HW2, NCELL2, NCELL0 + NCELL1>(p2, marks, 1.f / (float)NCELL2, acc, gtid, gstride);

    __shared__ float red[256];
    int tid = threadIdx.x;
    red[tid] = acc; __syncthreads();
    for (int off = 128; off > 0; off >>= 1) { if (tid < off) red[tid] += red[tid + off]; __syncthreads(); }

    if (tid == 0) {
        atomicAdd(acc_obj, red[0]);
        __threadfence();
        unsigned int prev = atomicAdd(counter, 1u);
        if (prev == gridDim.x - 1) {
            __threadfence();
            float obj = __hip_atomic_load(acc_obj, __ATOMIC_RELAXED, __HIP_MEMORY_SCOPE_AGENT);
            float box = 0.f, cls = 0.f;
            for (int i = 0; i < nblocks_t; i++) { box += box_part[i]; cls += cls_part[i]; }
            box *= inv_n;
            cls *= inv_n;
            out[0] = box + obj + cls;
            out[1] = box;
            out[2] = obj;
            out[3] = cls;
        }
    }
}

extern "C" void kernel_launch(void* const* d_in, const int* in_sizes, int n_in,
                              void* d_out, int out_size, void* d_ws, size_t ws_size,
                              hipStream_t stream) {
    const float* p0  = (const float*)d_in[0];
    const float* p1  = (const float*)d_in[1];
    const float* p2  = (const float*)d_in[2];
    const float* tgt = (const float*)d_in[3];
    int n = in_sizes[3] / 6;

    char* ws = (char*)d_ws;
    // ws layout:
    //   [0]                : float acc_obj
    //   [4]                : uint counter
    //   [256 .. 256+512*4) : box partials (float, up to 512 blocks)
    //   [2304.. )          : cls partials (float, up to 512 blocks)
    //   [8192.. 8192+268800): mark bytes
    float*        acc_obj  = (float*)ws;
    unsigned int* counter  = (unsigned int*)(ws + 4);
    float*        box_part = (float*)(ws + 256);
    float*        cls_part = (float*)(ws + 256 + 512 * 4);
    unsigned char* marks   = (unsigned char*)(ws + 8192);

    int nblocks_t = (n * 16 + 255) / 256;   // 128 for n=2048

    k_zero<<<64, 256, 0, stream>>>((unsigned int*)marks, NCELL_TOT / 4, acc_obj, counter);
    k_targets<<<nblocks_t, 256, 0, stream>>>(p0, p1, p2, tgt, n, box_part, cls_part, marks);
    float inv_n = 1.f / (float)((n > 1) ? n : 1);
    k_obj<<<OBJ_BLOCKS, 256, 0, stream>>>(p0, p1, p2, marks, box_part, cls_part,
                                          nblocks_t, inv_n, acc_obj, counter, (float*)d_out);
}

// Round 2
// 23.528 us; speedup vs baseline: 1.3370x; 1.3370x over previous
//
#include <hip/hip_runtime.h>

#define NC   80
#define CCH  85
#define NBATCH 32

#define HW0 6400
#define HW1 1600
#define HW2 400
#define NCELL0 (NBATCH*HW0)   // 204800
#define NCELL1 (NBATCH*HW1)   // 51200
#define NCELL2 (NBATCH*HW2)   // 12800
#define NCELL_TOT (NCELL0+NCELL1+NCELL2)  // 268800
#define BMWORDS ((NCELL_TOT+31)/32)       // 8400 words = 33.6KB LDS bitmap

#define MAXSLOTS 1024

static __device__ __forceinline__ float softplus_ref(float x) {
    return fmaxf(x, 0.f) + log1pf(expf(-fabsf(x)));
}

template <int HW, int NCELLS>
static __device__ __forceinline__ void obj_scale_loop(
        const float* __restrict__ pred, float& acc, int gtid, int gstride) {
    const int NG = NCELLS / 4;
    const float inv_norm = 1.f / (float)NCELLS;
    for (int g = gtid; g < NG; g += gstride) {
        int cell = g * 4;
        int b    = cell / HW;          // compile-time HW -> magic mul
        int pos  = cell - b * HW;
        const float4 x4 = *reinterpret_cast<const float4*>(
            pred + (size_t)b * CCH * HW + (size_t)4 * HW + pos);
        float ssum = softplus_ref(x4.x) + softplus_ref(x4.y)
                   + softplus_ref(x4.z) + softplus_ref(x4.w);
        acc += ssum * inv_norm;
    }
}

// K_A: dense obj softplus + per-target box/cls + block-0 dedup correction
__global__ void k_main(const float* __restrict__ p0, const float* __restrict__ p1,
                       const float* __restrict__ p2, const float* __restrict__ tgt,
                       int n,
                       float* __restrict__ box_part, float* __restrict__ cls_part,
                       float* __restrict__ objd_part, float* __restrict__ corr_out) {
    __shared__ unsigned int bitmap[BMWORDS];
    __shared__ float red[256];
    const int tid = threadIdx.x;

    // ---- dense softplus sweep over the 3 channel-4 planes (all blocks) ----
    float objd = 0.f;
    {
        int gtid    = blockIdx.x * blockDim.x + tid;
        int gstride = gridDim.x * blockDim.x;
        obj_scale_loop<HW0, NCELL0>(p0, objd, gtid, gstride);
        obj_scale_loop<HW1, NCELL1>(p1, objd, gtid, gstride);
        obj_scale_loop<HW2, NCELL2>(p2, objd, gtid, gstride);
    }

    // ---- per-target box + cls (16 lanes per target) ----
    float cls_sum = 0.f;
    float box_sum = 0.f;
    {
        int gid  = blockIdx.x * blockDim.x + tid;
        int t    = gid >> 4;
        int lane = gid & 15;
        if (t < n) {
            const float* tr = tgt + (size_t)t * 6;
            int   b   = (int)tr[0];
            int   cls = (int)tr[1];
            float cx = tr[2], cy = tr[3], bw = tr[4], bh = tr[5];

            float area = fmaxf(bw * bh, 1e-6f);
            int s = (area <= 0.01f) ? 0 : ((area <= 0.03f) ? 1 : 2);
            int w = 80 >> s, h = 80 >> s, hw = w * h;
            const float* pred = (s == 0) ? p0 : ((s == 1) ? p1 : p2);

            int gx = (int)(cx * (float)w); gx = min(max(gx, 0), w - 1);
            int gy = (int)(cy * (float)h); gy = min(max(gy, 0), h - 1);

            const float* base = pred + (size_t)b * CCH * hw + (size_t)gy * w + gx;

            #pragma unroll
            for (int k = 0; k < 5; k++) {
                int c = lane * 5 + k;
                float x  = base[(size_t)(5 + c) * hw];
                float tv = (c == cls) ? 1.f : 0.f;
                cls_sum += fmaxf(x, 0.f) - x * tv + log1pf(expf(-fabsf(x)));
            }
            cls_sum *= (1.f / (float)NC);

            if (lane == 0) {
                float pv0 = base[0];
                float pv1 = base[(size_t)hw];
                float pv2 = base[(size_t)2 * hw];
                float pv3 = base[(size_t)3 * hw];
                float px = (1.f / (1.f + expf(-pv0)) + (float)gx) / (float)w;
                float py = (1.f / (1.f + expf(-pv1)) + (float)gy) / (float)h;
                float pw = expf(fminf(pv2, 4.f)) / (float)w;
                float ph = expf(fminf(pv3, 4.f)) / (float)h;
                float l1 = (fabsf(px - cx) + fabsf(py - cy) + fabsf(pw - bw) + fabsf(ph - bh)) * 0.25f;
                float weight = 1.f + 2.f * (1.f - sqrtf(area));
                box_sum = l1 * weight;
            }
        }
    }

    // ---- block 0 only: dedup'd obj correction via LDS bitmap ----
    float corr = 0.f;
    if (blockIdx.x == 0) {
        for (int i = tid; i < BMWORDS; i += 256) bitmap[i] = 0u;
        __syncthreads();
        for (int t = tid; t < n; t += 256) {
            const float* tr = tgt + (size_t)t * 6;
            int   b  = (int)tr[0];
            float cx = tr[2], cy = tr[3], bw = tr[4], bh = tr[5];
            float area = fmaxf(bw * bh, 1e-6f);
            int s = (area <= 0.01f) ? 0 : ((area <= 0.03f) ? 1 : 2);
            int w = 80 >> s, h = 80 >> s, hw = w * h;
            const float* pred = (s == 0) ? p0 : ((s == 1) ? p1 : p2);
            float invn = (s == 0) ? (1.f / (float)NCELL0)
                       : ((s == 1) ? (1.f / (float)NCELL1) : (1.f / (float)NCELL2));
            int gx = (int)(cx * (float)w); gx = min(max(gx, 0), w - 1);
            int gy = (int)(cy * (float)h); gy = min(max(gy, 0), h - 1);
            int cellbase = (s == 0) ? 0 : ((s == 1) ? NCELL0 : (NCELL0 + NCELL1));
            int cell = cellbase + b * hw + gy * w + gx;
            unsigned int bit = 1u << (cell & 31);
            unsigned int old = atomicOr(&bitmap[cell >> 5], bit);
            if (!(old & bit)) {
                float x = pred[(size_t)b * CCH * hw + (size_t)4 * hw + (size_t)gy * w + gx];
                corr += x * invn;   // value depends only on cell -> deterministic
            }
        }
        __syncthreads();
    }

    // ---- per-block deterministic reductions -> own slot ----
    red[tid] = cls_sum; __syncthreads();
    for (int off = 128; off > 0; off >>= 1) { if (tid < off) red[tid] += red[tid + off]; __syncthreads(); }
    if (tid == 0) cls_part[blockIdx.x] = red[0];
    __syncthreads();
    red[tid] = box_sum; __syncthreads();
    for (int off = 128; off > 0; off >>= 1) { if (tid < off) red[tid] += red[tid + off]; __syncthreads(); }
    if (tid == 0) box_part[blockIdx.x] = red[0];
    __syncthreads();
    red[tid] = objd; __syncthreads();
    for (int off = 128; off > 0; off >>= 1) { if (tid < off) red[tid] += red[tid + off]; __syncthreads(); }
    if (tid == 0) objd_part[blockIdx.x] = red[0];
    if (blockIdx.x == 0) {
        __syncthreads();
        red[tid] = corr; __syncthreads();
        for (int off = 128; off > 0; off >>= 1) { if (tid < off) red[tid] += red[tid + off]; __syncthreads(); }
        if (tid == 0) corr_out[0] = red[0];
    }
}

// K_B: finalize (stream order guarantees K_A done; no counters needed)
__global__ void k_final(const float* __restrict__ box_part, const float* __restrict__ cls_part,
                        const float* __restrict__ objd_part, const float* __restrict__ corr,
                        int nb, float inv_n, float* __restrict__ out) {
    __shared__ float red[256];
    const int tid = threadIdx.x;
    float bs = 0.f, cs = 0.f, os = 0.f;
    for (int i = tid; i < nb; i += 256) {
        bs += box_part[i];
        cs += cls_part[i];
        os += objd_part[i];
    }
    red[tid] = bs; __syncthreads();
    for (int off = 128; off > 0; off >>= 1) { if (tid < off) red[tid] += red[tid + off]; __syncthreads(); }
    bs = red[0]; __syncthreads();
    red[tid] = cs; __syncthreads();
    for (int off = 128; off > 0; off >>= 1) { if (tid < off) red[tid] += red[tid + off]; __syncthreads(); }
    cs = red[0]; __syncthreads();
    red[tid] = os; __syncthreads();
    for (int off = 128; off > 0; off >>= 1) { if (tid < off) red[tid] += red[tid + off]; __syncthreads(); }
    os = red[0];
    if (tid == 0) {
        float box = bs * inv_n;
        float cls = cs * inv_n;
        float obj = os - corr[0];
        out[0] = box + obj + cls;
        out[1] = box;
        out[2] = obj;
        out[3] = cls;
    }
}

extern "C" void kernel_launch(void* const* d_in, const int* in_sizes, int n_in,
                              void* d_out, int out_size, void* d_ws, size_t ws_size,
                              hipStream_t stream) {
    const float* p0  = (const float*)d_in[0];
    const float* p1  = (const float*)d_in[1];
    const float* p2  = (const float*)d_in[2];
    const float* tgt = (const float*)d_in[3];
    int n = in_sizes[3] / 6;

    char* ws = (char*)d_ws;
    float* box_part  = (float*)ws;
    float* cls_part  = (float*)(ws + MAXSLOTS * 4);
    float* objd_part = (float*)(ws + 2 * MAXSLOTS * 4);
    float* corr      = (float*)(ws + 3 * MAXSLOTS * 4);

    int nb = (n * 16 + 255) / 256;       // 128 for n=2048
    if (nb < 64) nb = 64;
    if (nb > MAXSLOTS) nb = MAXSLOTS;    // (n<=16384 in practice)

    float inv_n = 1.f / (float)((n > 1) ? n : 1);

    k_main<<<nb, 256, 0, stream>>>(p0, p1, p2, tgt, n, box_part, cls_part, objd_part, corr);
    k_final<<<1, 256, 0, stream>>>(box_part, cls_part, objd_part, corr, nb, inv_n, (float*)d_out);
}